// Round 2
// baseline (265.638 us; speedup 1.0000x reference)
//
#include <hip/hip_runtime.h>

#define MDIM 8192
#define NDIM 8192
#define KDIM 64

typedef __attribute__((ext_vector_type(8))) short bf16x8;
typedef __attribute__((ext_vector_type(4))) float f32x4;

__device__ __forceinline__ unsigned short f32_to_bf16(float f) {
    union { float f; unsigned int u; } v;
    v.f = f;
    unsigned int u = v.u;
    u += 0x7FFFu + ((u >> 16) & 1u);  // round-to-nearest-even
    return (unsigned short)(u >> 16);
}

// global -> LDS direct copy, 16B per lane. LDS operand must be wave-uniform
// (HW uses base + lane*16); global operand is per-lane.
typedef const __attribute__((address_space(1))) unsigned int gas_u32;
typedef __attribute__((address_space(3))) unsigned int las_u32;
__device__ __forceinline__ void g2l16(const void* g, void* l) {
    __builtin_amdgcn_global_load_lds((gas_u32*)g, (las_u32*)l, 16, 0, 0);
}

// ---------------------------------------------------------------------------
// Prep kernel: convert A and B^T to bf16, tiled + XOR-swizzled, into ws.
//   wsA = ws[0 .. 64*8192)        : 64 m-tiles, tile t = A[t*128..+127][0..63]
//   wsB = ws[64*8192 .. 128*8192) : 64 n-tiles, tile t = B^T[t*128..+127][0..63]
// Within a tile (ushort units): elem (r, k) at  r*64 + ((k>>3)^(r&7))*8 + (k&7)
// The XOR granule swizzle makes the main kernel's ds_read_b128 fragment reads
// (16 rows x same granule) hit all 32 banks uniformly (residual 2-way = free).
// ---------------------------------------------------------------------------
__global__ __launch_bounds__(256, 8)
void prep_kernel(const float* __restrict__ A, const float* __restrict__ B,
                 unsigned short* __restrict__ ws) {
    const int tid = threadIdx.x;
    const int bid = blockIdx.x;
    if (bid < 64) {
        // A tile: coalesced float4 reads, row-major.
        const int m0 = bid << 7;
        const int row_base = tid >> 4;       // 0..15
        const int col = (tid & 15) << 2;     // 0,4,...,60
        const int gsw = ((col >> 3) ^ 0) << 3;  // granule base (row XOR added below)
        (void)gsw;
#pragma unroll
        for (int i = 0; i < 8; ++i) {
            const int row = row_base + (i << 4);
            const float4 v =
                *reinterpret_cast<const float4*>(&A[(size_t)(m0 + row) * KDIM + col]);
            ushort4 h;
            h.x = f32_to_bf16(v.x);
            h.y = f32_to_bf16(v.y);
            h.z = f32_to_bf16(v.z);
            h.w = f32_to_bf16(v.w);
            const size_t off = ((size_t)bid << 13) + row * 64 +
                               (((col >> 3) ^ (row & 7)) << 3) + (col & 7);
            *reinterpret_cast<ushort4*>(&ws[off]) = h;
        }
    } else {
        // B tile: read coalesced along n, write transposed [n][k].
        const int bt = bid - 64;
        const int n0 = bt << 7;
#pragma unroll
        for (int i = 0; i < 8; ++i) {
            const int n = (tid & 63) + ((i & 1) << 6);            // 0..127
            const int k0 = ((tid >> 6) << 2) + ((i >> 1) << 4);   // 0,4,...,60
            const size_t gb = (size_t)k0 * NDIM + n0 + n;
            ushort4 h;
            h.x = f32_to_bf16(B[gb]);
            h.y = f32_to_bf16(B[gb + NDIM]);
            h.z = f32_to_bf16(B[gb + 2 * NDIM]);
            h.w = f32_to_bf16(B[gb + 3 * NDIM]);
            const size_t off = ((size_t)(64 + bt) << 13) + n * 64 +
                               (((k0 >> 3) ^ (n & 7)) << 3) + (k0 & 7);
            *reinterpret_cast<ushort4*>(&ws[off]) = h;
        }
    }
}

// ---------------------------------------------------------------------------
// Main kernel: stage pre-swizzled bf16 tiles via global_load_lds (zero VALU,
// zero ds_write), 32 MFMA, then the contiguous-store LDS-bounce epilogue.
// ---------------------------------------------------------------------------
__global__ __launch_bounds__(256, 4)
void tmatmul_kernel(const unsigned short* __restrict__ ws, float* __restrict__ C) {
    // 32 KB: sA tile bytes [0,16384), sB tile bytes [16384,32768).
    // Recycled post-compute as 4 x 8 KB per-wave C bounce slabs.
    __shared__ __align__(16) unsigned short smem[16384];

    const int tid = threadIdx.x;
    const int lane = tid & 63;
    const int wv = tid >> 6;

    const unsigned short* gA = ws + ((size_t)blockIdx.y << 13);
    const unsigned short* gB = ws + ((size_t)(64 + blockIdx.x) << 13);

    // ---- Stage: identity copy of two 16 KB pre-swizzled tiles. 8 instrs. ----
    {
        const int base = wv << 12;  // bytes; each wave owns 4 KB of each tile
#pragma unroll
        for (int i = 0; i < 4; ++i) {
            const int off = base + (i << 10);
            g2l16((const char*)gA + off + lane * 16, (char*)smem + off);
            g2l16((const char*)gB + off + lane * 16, (char*)smem + 16384 + off);
        }
    }
    __syncthreads();

    const int l15 = lane & 15;
    const int quad = lane >> 4;
    const int x = l15 & 7;       // row-dependent XOR key (rows stride 16)
    const int wm = (wv >> 1) << 6;
    const int wn = (wv & 1) << 6;
    const char* sAb = (const char*)smem;
    const char* sBb = (const char*)smem + 16384;

    bf16x8 afrag[4][2];
#pragma unroll
    for (int mt = 0; mt < 4; ++mt)
#pragma unroll
        for (int ks = 0; ks < 2; ++ks)
            afrag[mt][ks] = *reinterpret_cast<const bf16x8*>(
                sAb + (wm + mt * 16 + l15) * 128 + (((ks * 4 + quad) ^ x) << 4));

    f32x4 acc[4][4];
    const f32x4 zero = {0.0f, 0.0f, 0.0f, 0.0f};
#pragma unroll
    for (int mt = 0; mt < 4; ++mt)
#pragma unroll
        for (int nt = 0; nt < 4; ++nt)
            acc[mt][nt] = zero;

    // Operand swap: D = (B^T-frag) x (A^T-frag) = C^T tile. Lane holds
    // C[m = l15][n = quad*4 + reg].
#pragma unroll
    for (int nt = 0; nt < 4; ++nt) {
        const char* rb = sBb + (wn + nt * 16 + l15) * 128;
        const bf16x8 bf0 = *reinterpret_cast<const bf16x8*>(rb + ((quad ^ x) << 4));
        const bf16x8 bf1 =
            *reinterpret_cast<const bf16x8*>(rb + (((quad + 4) ^ x) << 4));
#pragma unroll
        for (int mt = 0; mt < 4; ++mt) {
            acc[mt][nt] = __builtin_amdgcn_mfma_f32_16x16x32_bf16(
                bf0, afrag[mt][0], acc[mt][nt], 0, 0, 0);
            acc[mt][nt] = __builtin_amdgcn_mfma_f32_16x16x32_bf16(
                bf1, afrag[mt][1], acc[mt][nt], 0, 0, 0);
        }
    }

    // Waves must finish reading sA/sB before LDS is recycled as bounce space.
    __syncthreads();

    // ---- Epilogue: per-wave swizzled LDS bounce -> fully contiguous stores.
    // Each wave scatters one 16x64 mt-slice into its 4 KB slab (granule g at
    // row r stored at g^r -> conflict-free b128), re-reads row-major, stores
    // 4 rows x 256 B contiguous per global_store_dwordx4 (full 128 B lines).
    const int m0 = blockIdx.y << 7;
    const int n0 = blockIdx.x << 7;
    float* cw = reinterpret_cast<float*>(smem) + (wv << 11);  // 8 KB per wave
#pragma unroll
    for (int mt = 0; mt < 4; ++mt) {
        float* buf = cw + ((mt & 1) << 10);  // ping-pong 4 KB halves
#pragma unroll
        for (int nt = 0; nt < 4; ++nt) {
            const int g = (nt << 2) + quad;
            *reinterpret_cast<f32x4*>(&buf[(l15 << 6) + ((g ^ l15) << 2)]) =
                acc[mt][nt];
        }
        const int m_base = m0 + wm + (mt << 4);
        const int n_base = n0 + wn + (l15 << 2);
#pragma unroll
        for (int j = 0; j < 4; ++j) {
            const int rr = (j << 2) + quad;
            const f32x4 v = *reinterpret_cast<const f32x4*>(
                &buf[(rr << 6) + ((l15 ^ rr) << 2)]);
            __builtin_nontemporal_store(
                v, reinterpret_cast<f32x4*>(&C[(size_t)(m_base + rr) * NDIM + n_base]));
        }
    }
}

// ---------------------------------------------------------------------------
// Fallback (ws too small): round-1 single-kernel version.
// ---------------------------------------------------------------------------
#define LDS_STRIDE 72
__global__ __launch_bounds__(256, 3)
void tmatmul_fallback(const float* __restrict__ A, const float* __restrict__ B,
                      float* __restrict__ C) {
    __shared__ __align__(16) unsigned short smem[2 * 128 * LDS_STRIDE];
    unsigned short* sA = smem;
    unsigned short* sB = smem + 128 * LDS_STRIDE;

    const int tid = threadIdx.x;
    const int m0 = blockIdx.y << 7;
    const int n0 = blockIdx.x << 7;
    {
        const int row_base = tid >> 4;
        const int col = (tid & 15) << 2;
#pragma unroll
        for (int i = 0; i < 8; ++i) {
            const int row = row_base + (i << 4);
            const float4 v =
                *reinterpret_cast<const float4*>(&A[(size_t)(m0 + row) * KDIM + col]);
            ushort4 h;
            h.x = f32_to_bf16(v.x);
            h.y = f32_to_bf16(v.y);
            h.z = f32_to_bf16(v.z);
            h.w = f32_to_bf16(v.w);
            *reinterpret_cast<ushort4*>(&sA[row * LDS_STRIDE + col]) = h;
        }
    }
    {
#pragma unroll
        for (int i = 0; i < 8; ++i) {
            const int n = (tid & 63) + ((i & 1) << 6);
            const int k0 = ((tid >> 6) << 2) + ((i >> 1) << 4);
            const size_t gb = (size_t)k0 * NDIM + n0 + n;
            ushort4 h;
            h.x = f32_to_bf16(B[gb]);
            h.y = f32_to_bf16(B[gb + NDIM]);
            h.z = f32_to_bf16(B[gb + 2 * NDIM]);
            h.w = f32_to_bf16(B[gb + 3 * NDIM]);
            *reinterpret_cast<ushort4*>(&sB[n * LDS_STRIDE + k0]) = h;
        }
    }
    __syncthreads();

    const int lane = tid & 63;
    const int wv = tid >> 6;
    const int wm = (wv >> 1) << 6;
    const int wn = (wv & 1) << 6;
    const int l15 = lane & 15;
    const int quad = lane >> 4;

    bf16x8 afrag[4][2];
#pragma unroll
    for (int mt = 0; mt < 4; ++mt)
#pragma unroll
        for (int ks = 0; ks < 2; ++ks)
            afrag[mt][ks] = *reinterpret_cast<const bf16x8*>(
                &sA[(wm + mt * 16 + l15) * LDS_STRIDE + ks * 32 + quad * 8]);

    f32x4 acc[4][4];
    const f32x4 zero = {0.0f, 0.0f, 0.0f, 0.0f};
#pragma unroll
    for (int mt = 0; mt < 4; ++mt)
#pragma unroll
        for (int nt = 0; nt < 4; ++nt)
            acc[mt][nt] = zero;

#pragma unroll
    for (int nt = 0; nt < 4; ++nt) {
        const bf16x8 bf0 = *reinterpret_cast<const bf16x8*>(
            &sB[(wn + nt * 16 + l15) * LDS_STRIDE + quad * 8]);
        const bf16x8 bf1 = *reinterpret_cast<const bf16x8*>(
            &sB[(wn + nt * 16 + l15) * LDS_STRIDE + 32 + quad * 8]);
#pragma unroll
        for (int mt = 0; mt < 4; ++mt) {
            acc[mt][nt] = __builtin_amdgcn_mfma_f32_16x16x32_bf16(
                bf0, afrag[mt][0], acc[mt][nt], 0, 0, 0);
            acc[mt][nt] = __builtin_amdgcn_mfma_f32_16x16x32_bf16(
                bf1, afrag[mt][1], acc[mt][nt], 0, 0, 0);
        }
    }

    __syncthreads();

    float* cw = reinterpret_cast<float*>(smem) + (wv << 11);
#pragma unroll
    for (int mt = 0; mt < 4; ++mt) {
        float* buf = cw + ((mt & 1) << 10);
#pragma unroll
        for (int nt = 0; nt < 4; ++nt) {
            const int g = (nt << 2) + quad;
            *reinterpret_cast<f32x4*>(&buf[(l15 << 6) + ((g ^ l15) << 2)]) =
                acc[mt][nt];
        }
        const int m_base = m0 + wm + (mt << 4);
        const int n_base = n0 + wn + (l15 << 2);
#pragma unroll
        for (int j = 0; j < 4; ++j) {
            const int rr = (j << 2) + quad;
            const f32x4 v = *reinterpret_cast<const f32x4*>(
                &buf[(rr << 6) + ((l15 ^ rr) << 2)]);
            __builtin_nontemporal_store(
                v, reinterpret_cast<f32x4*>(&C[(size_t)(m_base + rr) * NDIM + n_base]));
        }
    }
}

extern "C" void kernel_launch(void* const* d_in, const int* in_sizes, int n_in,
                              void* d_out, int out_size, void* d_ws, size_t ws_size,
                              hipStream_t stream) {
    const float* A = (const float*)d_in[0];
    const float* B = (const float*)d_in[1];
    float* C = (float*)d_out;
    const size_t ws_needed = (size_t)128 * 8192 * sizeof(unsigned short);  // 2 MB
    if (d_ws != nullptr && ws_size >= ws_needed) {
        prep_kernel<<<dim3(128, 1, 1), dim3(256, 1, 1), 0, stream>>>(
            A, B, (unsigned short*)d_ws);
        dim3 grid(NDIM / 128, MDIM / 128);
        tmatmul_kernel<<<grid, dim3(256, 1, 1), 0, stream>>>(
            (const unsigned short*)d_ws, C);
    } else {
        dim3 grid(NDIM / 128, MDIM / 128);
        tmatmul_fallback<<<grid, dim3(256, 1, 1), 0, stream>>>(A, B, C);
    }
}